// Round 4
// baseline (28.395 us; speedup 1.0000x reference)
//
#include <hip/hip_runtime.h>

// FocalLoss (sigmoid focal, mean reduction) — pure-streaming layout.
//   cls_score: [N=4, C=19, H=512, W=512] float32  (80 MB, read once, linear)
//   label:     [N=4, H=512, W=512] int32          (4 MB, read 19x, L2-local)
// One thread per float4 of cls. blocks-per-(n,c)-plane = HW/1024 = 256, so
// grid = 4*19*256 = 19456 and all (n,c,pix) math is scalar per-block.
// The 19 blocks sharing a pixel chunk differ by multiples of 256 in blockIdx
// -> same XCD (bid % 8 equal) -> label quad reuse hits that XCD's L2.
// Two-stage deterministic reduction (partials in d_ws).

#define NC 19
#define IGNORE_INDEX 255
#define ALPHA 0.25f

constexpr int NBATCH = 4;
constexpr int HW = 512 * 512;                    // 2^18
constexpr int BLOCK = 256;
constexpr int BPP = HW / (BLOCK * 4);            // blocks per plane = 256
constexpr int GRID = NBATCH * NC * BPP;          // 19456
constexpr int BLOCK2 = 1024;
constexpr float INV_TOTAL = 1.0f / (float)(NBATCH * NC * HW);

template <int NWAVE>
__device__ __forceinline__ float block_reduce(float v, float* smem) {
    #pragma unroll
    for (int off = 32; off > 0; off >>= 1)
        v += __shfl_down(v, off, 64);
    const int lane = threadIdx.x & 63;
    const int wid  = threadIdx.x >> 6;
    if (lane == 0) smem[wid] = v;
    __syncthreads();
    float s = 0.0f;
    if (threadIdx.x == 0) {
        #pragma unroll
        for (int i = 0; i < NWAVE; ++i) s += smem[i];
    }
    return s;  // valid in thread 0 only
}

__global__ __launch_bounds__(BLOCK) void focal_partial(
        const float* __restrict__ x,
        const int*   __restrict__ label,
        float*       __restrict__ partial) {
    const int b     = blockIdx.x;
    const int plane = b >> 8;            // n*NC + c, 0..75  (scalar)
    const int k     = b & 255;           // pixel-chunk within plane (scalar)
    const int c     = plane % NC;        // scalar div-by-19 (magic mul)
    const int n     = plane / NC;
    const int pix   = (k << 10) + (threadIdx.x << 2);

    const float4 v  = *reinterpret_cast<const float4*>(
                          x + ((size_t)plane << 18) + pix);
    const int4   l4 = *reinterpret_cast<const int4*>(
                          label + ((size_t)n << 18) + pix);
    const int lab[4] = {l4.x, l4.y, l4.z, l4.w};
    const float xs[4] = {v.x, v.y, v.z, v.w};

    float acc = 0.0f;
    #pragma unroll
    for (int j = 0; j < 4; ++j) {
        const float xv   = xs[j];
        const bool  val  = (lab[j] >= 0) && (lab[j] != IGNORE_INDEX);
        const bool  t    = (lab[j] == c);
        const float d    = t ? (1.0f - xv) : xv;
        float w          = ALPHA * d * d;
        w                = val ? w : 0.0f;
        // bce_with_logits: max(x,0) - x*t + log1p(exp(-|x|))
        const float sp   = __logf(1.0f + __expf(-fabsf(xv)));
        const float bce  = fmaxf(xv, 0.0f) - (t ? xv : 0.0f) + sp;
        acc = fmaf(bce, w, acc);
    }

    __shared__ float smem[BLOCK / 64];
    const float s = block_reduce<BLOCK / 64>(acc, smem);
    if (threadIdx.x == 0) partial[b] = s;
}

__global__ __launch_bounds__(BLOCK2) void focal_finalize(
        const float* __restrict__ partial,
        float*       __restrict__ out) {
    float acc = 0.0f;
    for (int i = threadIdx.x; i < GRID; i += BLOCK2)
        acc += partial[i];
    __shared__ float smem[BLOCK2 / 64];
    const float s = block_reduce<BLOCK2 / 64>(acc, smem);
    if (threadIdx.x == 0) out[0] = s * INV_TOTAL;  // LOSS_WEIGHT == 1.0
}

extern "C" void kernel_launch(void* const* d_in, const int* in_sizes, int n_in,
                              void* d_out, int out_size, void* d_ws, size_t ws_size,
                              hipStream_t stream) {
    const float* cls_score = (const float*)d_in[0];
    const int*   label     = (const int*)d_in[1];
    float* out     = (float*)d_out;
    float* partial = (float*)d_ws;   // GRID floats = 76 KB

    focal_partial<<<GRID, BLOCK, 0, stream>>>(cls_score, label, partial);
    focal_finalize<<<1, BLOCK2, 0, stream>>>(partial, out);
}

// Round 6
// 25.497 us; speedup vs baseline: 1.1137x; 1.1137x over previous
//
#include <hip/hip_runtime.h>

// FocalLoss (sigmoid focal, mean reduction).
//   cls_score: [N=4, C=19, H=512, W=512] float32  (80 MB, streamed once, nontemporal)
//   label:     [N=4, H=512, W=512] int32          (4 MB, re-read 19x, L2/L3-cached)
// Persistent grid-stride partial kernel. 2048 blocks x 256 thr (8 blocks/CU),
// each thread walks flat float4-quad index with stride, unroll-2 -> 2 cls loads +
// 2 label loads independent and in flight; block_reduce paid once per thread.
// Flat quad q: plane = q>>16 (n*19+c), pixq = q&65535. Consecutive planes share
// the same label plane (c varies fastest) -> label reuse is cache-hot.
// Two-stage deterministic reduction.
// R6 fix: __builtin_nontemporal_load needs native (ext_vector) types, not
// HIP_vector_type — use f32x4/i32x4 typedefs.

#define NC 19
#define IGNORE_INDEX 255
#define ALPHA 0.25f

typedef float f32x4 __attribute__((ext_vector_type(4)));
typedef int   i32x4 __attribute__((ext_vector_type(4)));

constexpr int NBATCH = 4;
constexpr int HW = 512 * 512;                       // 2^18
constexpr int NQ = NBATCH * NC * (HW / 4);          // 4,980,736 float4-quads
constexpr int BLOCK = 256;
constexpr int GRID = 2048;                          // 8 blocks/CU
constexpr int TT = GRID * BLOCK;                    // 524,288 threads
constexpr int BLOCK2 = 1024;
constexpr float INV_TOTAL = 1.0f / (float)(NBATCH * NC * HW);

template <int NWAVE>
__device__ __forceinline__ float block_reduce(float v, float* smem) {
    #pragma unroll
    for (int off = 32; off > 0; off >>= 1)
        v += __shfl_down(v, off, 64);
    const int lane = threadIdx.x & 63;
    const int wid  = threadIdx.x >> 6;
    if (lane == 0) smem[wid] = v;
    __syncthreads();
    float s = 0.0f;
    if (threadIdx.x == 0) {
        #pragma unroll
        for (int i = 0; i < NWAVE; ++i) s += smem[i];
    }
    return s;  // valid in thread 0 only
}

__device__ __forceinline__ float quad_loss(const f32x4 v, const i32x4 l4, const int c) {
    float acc = 0.0f;
    #pragma unroll
    for (int j = 0; j < 4; ++j) {
        const float xv  = v[j];
        const int   lb  = l4[j];
        const bool  val = (lb >= 0) && (lb != IGNORE_INDEX);
        const bool  t   = (lb == c);
        const float d   = t ? (1.0f - xv) : xv;
        float w         = ALPHA * d * d;
        w               = val ? w : 0.0f;
        // bce_with_logits: max(x,0) - x*t + log1p(exp(-|x|))
        const float sp  = __logf(1.0f + __expf(-fabsf(xv)));
        const float bce = fmaxf(xv, 0.0f) - (t ? xv : 0.0f) + sp;
        acc = fmaf(bce, w, acc);
    }
    return acc;
}

__global__ __launch_bounds__(BLOCK, 8) void focal_partial(
        const f32x4* __restrict__ x,
        const i32x4* __restrict__ lab4,      // label viewed as int4 quads
        float*       __restrict__ partial) {
    const int tid = blockIdx.x * BLOCK + threadIdx.x;

    float acc = 0.0f;
    for (int q = tid; q < NQ; q += 2 * TT) {
        // ---- iteration A (always in range) ----
        const unsigned plane0 = (unsigned)q >> 16;
        const int      pixq0  = q & 65535;
        const unsigned n0     = plane0 / NC;         // magic-mul div
        const int      c0     = (int)(plane0 - n0 * NC);
        const f32x4    v0     = __builtin_nontemporal_load(x + q);
        const i32x4    l0     = lab4[((size_t)n0 << 16) + pixq0];

        // ---- iteration B (wave-uniform guard) ----
        const int q1 = q + TT;
        if (q1 < NQ) {
            const unsigned plane1 = (unsigned)q1 >> 16;
            const int      pixq1  = q1 & 65535;
            const unsigned n1     = plane1 / NC;
            const int      c1     = (int)(plane1 - n1 * NC);
            const f32x4    v1     = __builtin_nontemporal_load(x + q1);
            const i32x4    l1     = lab4[((size_t)n1 << 16) + pixq1];
            acc += quad_loss(v0, l0, c0);
            acc += quad_loss(v1, l1, c1);
        } else {
            acc += quad_loss(v0, l0, c0);
        }
    }

    __shared__ float smem[BLOCK / 64];
    const float s = block_reduce<BLOCK / 64>(acc, smem);
    if (threadIdx.x == 0) partial[blockIdx.x] = s;
}

__global__ __launch_bounds__(BLOCK2) void focal_finalize(
        const float* __restrict__ partial,
        float*       __restrict__ out) {
    float acc = 0.0f;
    for (int i = threadIdx.x; i < GRID; i += BLOCK2)
        acc += partial[i];
    __shared__ float smem[BLOCK2 / 64];
    const float s = block_reduce<BLOCK2 / 64>(acc, smem);
    if (threadIdx.x == 0) out[0] = s * INV_TOTAL;  // LOSS_WEIGHT == 1.0
}

extern "C" void kernel_launch(void* const* d_in, const int* in_sizes, int n_in,
                              void* d_out, int out_size, void* d_ws, size_t ws_size,
                              hipStream_t stream) {
    const f32x4* cls_score = (const f32x4*)d_in[0];
    const i32x4* lab4      = (const i32x4*)d_in[1];
    float* out     = (float*)d_out;
    float* partial = (float*)d_ws;   // GRID floats = 8 KB

    focal_partial<<<GRID, BLOCK, 0, stream>>>(cls_score, lab4, partial);
    focal_finalize<<<1, BLOCK2, 0, stream>>>(partial, out);
}